// Round 4
// baseline (2881.686 us; speedup 1.0000x reference)
//
#include <hip/hip_runtime.h>
#include <math.h>

// Problem constants
#define B_    32
#define T_    21
#define STEPS 20
#define V_    10000
#define E_    512
#define A_    512
#define L_    512
#define P_    196
#define ENC_  2048
#define XK_   3072   // E + ENC + L (h appended for fused z GEMM)
#define ZN_   2048   // 4*L
#define ZCH   24     // K-chunks for z GEMM (3072/128)

// ---- workspace layout (float offsets) ----
#define WS_ORD    0          // int[32]
#define WS_SLEN   32         // int[32]
#define WS_HBUF   64         // 2 * 32*512 -> end 32832
#define WS_CBUF   32832      // 2 * 32*512 -> end 65600
#define WS_ALPHA  65600      // 6272 -> 71872
#define WS_AWE    71872      // 65536 -> 137408
#define WS_X      137408     // 98304 -> 235712
#define WS_A1B    235712     // bf16 6272*512 = 1605632 fl -> 1841344
#define WS_WLUB   1841344    // bf16 3072*2048 = 3145728 fl -> 4987072
#define WS_WOB    4987072    // bf16 512*10000 = 2560000 fl -> 7547072
#define WS_WBB    7547072    // bf16 512*2048 = 524288 fl -> 8071360
#define WS_WGAB   8071360    // bf16 512*512 = 131072 fl -> 8202432
#define WS_UNION  8202432    // 1572864 fl -> 9775296 (39.10 MB total)
// union members (lifetimes strictly stream-ordered, no overlap in space+time):
#define WS_MEAN   (WS_UNION)                 // 65536 (prologue)
#define WS_PH     (WS_UNION + 65536)         // 524288 (prologue h0/c0 partials)
#define WS_WEAT   (WS_UNION + 1048576)       // 524288 fl = 1048576 bf16 (prologue->a1)
#define WS_PZ     (WS_UNION)                 // 24*65536 = 1572864 (step: z partials)
#define WS_PB     (WS_UNION)                 // 4*65536 (step: Wb partials, dead before PZ written)
#define WS_PP     (WS_UNION)                 // 4*320000 (step: Wo partials, after PZ consumed)

// ---- output layout (float offsets) ----
#define OUT_PRED  0
#define OUT_ALPHA 6400000    // 32*20*10000
#define OUT_ORDER 6525440    // + 32*20*196

typedef __attribute__((ext_vector_type(8))) short bf16x8;
typedef __attribute__((ext_vector_type(4))) float f32x4;
typedef unsigned short ushort_t;

__device__ inline unsigned f2bf2(float lo, float hi) {
    unsigned a = __float_as_uint(lo), b = __float_as_uint(hi);
    a = (a + 0x7FFFu + ((a >> 16) & 1u)) >> 16;
    b = (b + 0x7FFFu + ((b >> 16) & 1u)) >> 16;
    return a | (b << 16);
}
__device__ inline ushort_t f2bf(float f) {
    unsigned u = __float_as_uint(f);
    return (ushort_t)((u + 0x7FFFu + ((u >> 16) & 1u)) >> 16);
}
__device__ inline float bfs(ushort_t u) {            // scalar bf16 -> f32
    return __uint_as_float(((unsigned)u) << 16);
}
__device__ inline float bfu_lo(unsigned u) { return __uint_as_float(u << 16); }
__device__ inline float bfu_hi(unsigned u) { return __uint_as_float(u & 0xFFFF0000u); }

// ============ order / lengths (stable descending argsort) ============
__global__ void k_order(const int* __restrict__ seqs, int* __restrict__ ord,
                        int* __restrict__ slen, float* __restrict__ out_ord)
{
    __shared__ int len[B_];
    int i = threadIdx.x;
    if (i < B_) {
        int c = 0;
        for (int t = 0; t < T_; ++t) c += (seqs[i * T_ + t] != 0) ? 1 : 0;
        len[i] = c;
    }
    __syncthreads();
    if (i < B_) {
        int li = len[i], r = 0;
        for (int j = 0; j < B_; ++j) {
            int lj = len[j];
            if (lj > li || (lj == li && j < i)) ++r;
        }
        ord[r]  = i;
        slen[r] = li - 1;
        out_ord[r] = (float)i;
    }
}

// ============ mean-pool encoder (sorted) ============
__global__ void k_mean(const float* __restrict__ enc, const int* __restrict__ ord,
                       float* __restrict__ mean)
{
    int tid = blockIdx.x * 256 + threadIdx.x;   // 65536
    int b = tid >> 11, e = tid & 2047;
    const float* row = enc + (size_t)ord[b] * (P_ * ENC_) + e;
    float s = 0.f;
    for (int p = 0; p < P_; ++p) s += row[(size_t)p * ENC_];
    mean[tid] = s * (1.0f / 196.0f);
}

// ============ generic fp32 -> bf16 cast ============
__global__ void k_cast(const float* __restrict__ src, ushort_t* __restrict__ dst, int n)
{
    int i = blockIdx.x * 256 + threadIdx.x;
    if (i < n) dst[i] = f2bf(src[i]);
}

// ============ cast + transpose Wea -> WeaT bf16 [512][2048] ============
__global__ void k_castWT(const float* __restrict__ Wea, ushort_t* __restrict__ WT)
{
    int tid = blockIdx.x * 256 + threadIdx.x;   // 1048576
    int n = tid >> 11, k = tid & 2047;
    WT[tid] = f2bf(Wea[(size_t)k * 512 + n]);
}

// ============ a1 = enc_sorted @ Wea + bea via bf16 MFMA -> bf16 out ============
__global__ __launch_bounds__(256, 1) void k_a1_mfma(
    const float* __restrict__ enc, const ushort_t* __restrict__ WeaT,
    const float* __restrict__ bea, const int* __restrict__ ord,
    ushort_t* __restrict__ a1b)
{
    __shared__ ushort_t As[128 * 40];   // [row][k0..31], stride 40 (pad never read)
    __shared__ ushort_t Bs[128 * 40];
    const int tid = threadIdx.x;
    const int lane = tid & 63, wave = tid >> 6;
    const int m0 = blockIdx.x * 128;
    const int n0 = blockIdx.y * 128;

    const int c0 = tid, c1 = tid + 256;
    const int ar0 = c0 >> 2, ak0 = (c0 & 3) * 8;
    const int ar1 = c1 >> 2, ak1 = (c1 & 3) * 8;
    const int g0 = m0 + ar0, g1 = m0 + ar1;
    const float* Ag0 = enc + ((size_t)ord[g0 / P_] * P_ + (g0 % P_)) * ENC_ + ak0;
    const float* Ag1 = enc + ((size_t)ord[g1 / P_] * P_ + (g1 % P_)) * ENC_ + ak1;
    const ushort_t* Bg0 = WeaT + (size_t)(n0 + ar0) * ENC_ + ak0;
    const ushort_t* Bg1 = WeaT + (size_t)(n0 + ar1) * ENC_ + ak1;
    ushort_t* Aw0 = &As[ar0 * 40 + ak0];
    ushort_t* Aw1 = &As[ar1 * 40 + ak1];
    ushort_t* Bw0 = &Bs[ar0 * 40 + ak0];
    ushort_t* Bw1 = &Bs[ar1 * 40 + ak1];

    const int wm = (wave >> 1) * 64, wn = (wave & 1) * 64;
    f32x4 acc[4][4] = {};

    for (int k0 = 0; k0 < ENC_; k0 += 32) {
        float4 v0 = *reinterpret_cast<const float4*>(Ag0 + k0);
        float4 v1 = *reinterpret_cast<const float4*>(Ag0 + k0 + 4);
        float4 v2 = *reinterpret_cast<const float4*>(Ag1 + k0);
        float4 v3 = *reinterpret_cast<const float4*>(Ag1 + k0 + 4);
        uint4 pa0, pa1;
        pa0.x = f2bf2(v0.x, v0.y); pa0.y = f2bf2(v0.z, v0.w);
        pa0.z = f2bf2(v1.x, v1.y); pa0.w = f2bf2(v1.z, v1.w);
        pa1.x = f2bf2(v2.x, v2.y); pa1.y = f2bf2(v2.z, v2.w);
        pa1.z = f2bf2(v3.x, v3.y); pa1.w = f2bf2(v3.z, v3.w);
        uint4 pb0 = *reinterpret_cast<const uint4*>(Bg0 + k0);
        uint4 pb1 = *reinterpret_cast<const uint4*>(Bg1 + k0);
        __syncthreads();
        *reinterpret_cast<uint4*>(Aw0) = pa0;
        *reinterpret_cast<uint4*>(Aw1) = pa1;
        *reinterpret_cast<uint4*>(Bw0) = pb0;
        *reinterpret_cast<uint4*>(Bw1) = pb1;
        __syncthreads();
        {
            bf16x8 af[4], bfr[4];
            const int arow = wm + (lane & 15);
            const int brow = wn + (lane & 15);
            const int koff = (lane >> 4) * 8;
#pragma unroll
            for (int mt = 0; mt < 4; ++mt)
                af[mt] = *reinterpret_cast<const bf16x8*>(&As[(arow + mt * 16) * 40 + koff]);
#pragma unroll
            for (int nt = 0; nt < 4; ++nt)
                bfr[nt] = *reinterpret_cast<const bf16x8*>(&Bs[(brow + nt * 16) * 40 + koff]);
#pragma unroll
            for (int mt = 0; mt < 4; ++mt)
#pragma unroll
                for (int nt = 0; nt < 4; ++nt)
                    acc[mt][nt] = __builtin_amdgcn_mfma_f32_16x16x32_bf16(
                        af[mt], bfr[nt], acc[mt][nt], 0, 0, 0);
        }
    }
    const int rbase = (lane >> 4) * 4;
    const int cbase = lane & 15;
#pragma unroll
    for (int nt = 0; nt < 4; ++nt) {
        int col = n0 + wn + nt * 16 + cbase;
        float be = bea[col];
#pragma unroll
        for (int mt = 0; mt < 4; ++mt) {
            int row = m0 + wm + mt * 16 + rbase;
#pragma unroll
            for (int r = 0; r < 4; ++r)
                a1b[(size_t)(row + r) * 512 + col] = f2bf(acc[mt][nt][r] + be);
        }
    }
}

// ============ skinny GEMM partial (fp32 W) — prologue only ============
__global__ void sg_partial(const float* __restrict__ X, const float* __restrict__ W,
                           float* __restrict__ part, int K, int N, int kchunk, int chunk_ofs)
{
    const int n = blockIdx.x * 256 + threadIdx.x;
    const int c = blockIdx.y;
    const int bh = blockIdx.z;
    const int k0 = c * kchunk;
    int k1 = k0 + kchunk; if (k1 > K) k1 = K;
    float acc[16];
#pragma unroll
    for (int b = 0; b < 16; ++b) acc[b] = 0.f;
    if (n < N) {
        const float* Xb = X + (size_t)(bh * 16) * K;
        for (int k = k0; k < k1; k += 4) {
            float w0 = W[(size_t)(k + 0) * N + n];
            float w1 = W[(size_t)(k + 1) * N + n];
            float w2 = W[(size_t)(k + 2) * N + n];
            float w3 = W[(size_t)(k + 3) * N + n];
#pragma unroll
            for (int b = 0; b < 16; ++b) {
                const float4 xv = *reinterpret_cast<const float4*>(&Xb[(size_t)b * K + k]);
                acc[b] += xv.x * w0 + xv.y * w1 + xv.z * w2 + xv.w * w3;
            }
        }
        float* po = part + (size_t)(chunk_ofs + c) * (B_ * (size_t)N) + (size_t)(bh * 16) * N;
#pragma unroll
        for (int b = 0; b < 16; ++b) po[(size_t)b * N + n] = acc[b];
    }
}

// ============ skinny GEMM partial with bf16 weights (step loop) ============
__global__ void sg_bf(const float* __restrict__ X, const ushort_t* __restrict__ W,
                      float* __restrict__ part, int K, int N, int kchunk, int chunk_ofs)
{
    const int n = blockIdx.x * 256 + threadIdx.x;
    const int c = blockIdx.y;
    const int bh = blockIdx.z;
    const int k0 = c * kchunk;
    int k1 = k0 + kchunk; if (k1 > K) k1 = K;
    float acc[16];
#pragma unroll
    for (int b = 0; b < 16; ++b) acc[b] = 0.f;
    if (n < N) {
        const float* Xb = X + (size_t)(bh * 16) * K;
        for (int k = k0; k < k1; k += 4) {
            float w0 = bfs(W[(size_t)(k + 0) * N + n]);
            float w1 = bfs(W[(size_t)(k + 1) * N + n]);
            float w2 = bfs(W[(size_t)(k + 2) * N + n]);
            float w3 = bfs(W[(size_t)(k + 3) * N + n]);
#pragma unroll
            for (int b = 0; b < 16; ++b) {
                const float4 xv = *reinterpret_cast<const float4*>(&Xb[(size_t)b * K + k]);
                acc[b] += xv.x * w0 + xv.y * w1 + xv.z * w2 + xv.w * w3;
            }
        }
        float* po = part + (size_t)(chunk_ofs + c) * (B_ * (size_t)N) + (size_t)(bh * 16) * N;
#pragma unroll
        for (int b = 0; b < 16; ++b) po[(size_t)b * N + n] = acc[b];
    }
}

// ============ h0/c0 combine ============
__global__ void k_h0c0(const float* __restrict__ ph, const float* __restrict__ bim,
                       const float* __restrict__ bic, float* __restrict__ h0,
                       float* __restrict__ c0)
{
    int tid = blockIdx.x * 256 + threadIdx.x;   // 32768
    int half = tid >> 14;
    int idx = tid & 16383;
    int l = idx & 511;
    int cofs = half ? 16 : 0;
    float s = 0.f;
    for (int c = 0; c < 16; ++c) s += ph[(size_t)(cofs + c) * (B_ * 512) + idx];
    if (half) c0[idx] = s + bic[l];
    else      h0[idx] = s + bim[l];
}

// ============ fused attention: a2 GEMM (bf16 Wga) + e (bf16 a1) + softmax ============
__global__ __launch_bounds__(256, 1) void k_attn(
    const float* __restrict__ c_in, const ushort_t* __restrict__ WgaB,
    const float* __restrict__ bga, const float* __restrict__ Wfa,
    const float* __restrict__ bfa, const ushort_t* __restrict__ a1b,
    float* __restrict__ alpha, float* __restrict__ out_alpha,
    const int* __restrict__ slen, int t)
{
    __shared__ float cs[512];
    __shared__ float a2p[2][512];
    __shared__ float a2s[512];
    __shared__ float esh[224];
    __shared__ float red[256];
    const int b = blockIdx.x;
    const int tid = threadIdx.x;
    const int wave = tid >> 6, lane = tid & 63;

    cs[tid]       = c_in[b * 512 + tid];
    cs[tid + 256] = c_in[b * 512 + 256 + tid];
    __syncthreads();

    // ---- a2 = c @ Wga (bf16 weights, split K halves) ----
    {
        const int half = tid >> 7, tl = tid & 127;
        const int n4 = tl * 4;
        float4 acc = {0.f, 0.f, 0.f, 0.f};
        const ushort_t* wbase = WgaB + (size_t)(half * 256) * 512 + n4;
        for (int k = 0; k < 256; ++k) {
            float cv = cs[half * 256 + k];
            uint2 wr = *reinterpret_cast<const uint2*>(wbase + (size_t)k * 512);
            acc.x += cv * bfu_lo(wr.x); acc.y += cv * bfu_hi(wr.x);
            acc.z += cv * bfu_lo(wr.y); acc.w += cv * bfu_hi(wr.y);
        }
        *reinterpret_cast<float4*>(&a2p[half][n4]) = acc;
    }
    __syncthreads();
    if (tid < 128) {
        const int n4 = tid * 4;
        float4 p0 = *reinterpret_cast<const float4*>(&a2p[0][n4]);
        float4 p1 = *reinterpret_cast<const float4*>(&a2p[1][n4]);
        float4 g  = *reinterpret_cast<const float4*>(bga + n4);
        float4 r;
        r.x = p0.x + p1.x + g.x; r.y = p0.y + p1.y + g.y;
        r.z = p0.z + p1.z + g.z; r.w = p0.w + p1.w + g.w;
        *reinterpret_cast<float4*>(&a2s[n4]) = r;
    }
    __syncthreads();

    // ---- e[p] = relu(a1[p]+a2) . Wfa : 16 lanes per p, a1 in bf16 ----
    {
        const int grp = lane >> 4;
        const int sub = lane & 15;
        float4 a2r[4][2], wfr[4][2];
#pragma unroll
        for (int blk = 0; blk < 4; ++blk)
#pragma unroll
            for (int j = 0; j < 2; ++j) {
                int d = blk * 128 + sub * 8 + j * 4;
                a2r[blk][j] = *reinterpret_cast<const float4*>(&a2s[d]);
                wfr[blk][j] = *reinterpret_cast<const float4*>(Wfa + d);
            }
        const float bf0 = bfa[0];
        for (int pass = 0; pass < 13; ++pass) {
            const int p = pass * 16 + wave * 4 + grp;
            const int pc = p < P_ ? p : P_ - 1;
            const ushort_t* arow = a1b + ((size_t)b * P_ + pc) * 512;
            float s = 0.f;
#pragma unroll
            for (int blk = 0; blk < 4; ++blk) {
                uint4 raw = *reinterpret_cast<const uint4*>(arow + blk * 128 + sub * 8);
                float4 av = a2r[blk][0], wv = wfr[blk][0];
                float v;
                v = bfu_lo(raw.x) + av.x; v = v > 0.f ? v : 0.f; s += v * wv.x;
                v = bfu_hi(raw.x) + av.y; v = v > 0.f ? v : 0.f; s += v * wv.y;
                v = bfu_lo(raw.y) + av.z; v = v > 0.f ? v : 0.f; s += v * wv.z;
                v = bfu_hi(raw.y) + av.w; v = v > 0.f ? v : 0.f; s += v * wv.w;
                av = a2r[blk][1]; wv = wfr[blk][1];
                v = bfu_lo(raw.z) + av.x; v = v > 0.f ? v : 0.f; s += v * wv.x;
                v = bfu_hi(raw.z) + av.y; v = v > 0.f ? v : 0.f; s += v * wv.y;
                v = bfu_lo(raw.w) + av.z; v = v > 0.f ? v : 0.f; s += v * wv.z;
                v = bfu_hi(raw.w) + av.w; v = v > 0.f ? v : 0.f; s += v * wv.w;
            }
            s += __shfl_xor(s, 1, 64);
            s += __shfl_xor(s, 2, 64);
            s += __shfl_xor(s, 4, 64);
            s += __shfl_xor(s, 8, 64);
            if (sub == 0 && p < P_) esh[p] = s + bf0;
        }
    }
    __syncthreads();

    // ---- softmax over esh[0..195] ----
    float v = (tid < P_) ? esh[tid] : -1e30f;
    red[tid] = v; __syncthreads();
    for (int s2 = 128; s2 > 0; s2 >>= 1) {
        if (tid < s2) red[tid] = fmaxf(red[tid], red[tid + s2]);
        __syncthreads();
    }
    float mx = red[0]; __syncthreads();
    float ex = (tid < P_) ? expf(v - mx) : 0.f;
    red[tid] = ex; __syncthreads();
    for (int s2 = 128; s2 > 0; s2 >>= 1) {
        if (tid < s2) red[tid] += red[tid + s2];
        __syncthreads();
    }
    float inv = 1.0f / red[0];
    if (tid < P_) {
        float al = ex * inv;
        alpha[b * P_ + tid] = al;
        float mf = (slen[b] > t) ? 1.f : 0.f;
        out_alpha[((size_t)b * STEPS + t) * P_ + tid] = al * mf;
    }
}

// ============ awe[b][e] = sum_p alpha[b][p] * enc_sorted[b][p][e] ============
__global__ void k_awe(const float* __restrict__ alpha, const float* __restrict__ enc,
                      const int* __restrict__ ord, float* __restrict__ awe)
{
    int tid = blockIdx.x * 256 + threadIdx.x;   // 65536
    int b = tid >> 11, e = tid & 2047;
    const float* erow = enc + (size_t)ord[b] * (P_ * ENC_) + e;
    const float* al = alpha + b * P_;
    float s = 0.f;
    for (int p = 0; p < P_; ++p) s += al[p] * erow[(size_t)p * ENC_];
    awe[tid] = s;
}

// ============ x = [emb[tok], awe * sigmoid(c@Wb + bb), h_in] ============
__global__ void k_buildx(const float* __restrict__ pb, const float* __restrict__ bb,
                         const float* __restrict__ awe, const float* __restrict__ emb,
                         const int* __restrict__ seqs, const int* __restrict__ ord,
                         const float* __restrict__ h_in, int t, float* __restrict__ x)
{
    int tid = blockIdx.x * 256 + threadIdx.x;   // 98304
    int b = tid / XK_, j = tid - b * XK_;
    if (j < E_) {
        int tok = seqs[ord[b] * T_ + t];
        x[tid] = emb[(size_t)tok * E_ + j];
    } else if (j < E_ + ENC_) {
        int jj = j - E_;
        int idx = b * ENC_ + jj;
        float s = 0.f;
        for (int c = 0; c < 4; ++c) s += pb[(size_t)c * (B_ * ENC_) + idx];
        float beta = 1.0f / (1.0f + expf(-(s + bb[jj])));
        x[tid] = awe[idx] * beta;
    } else {
        x[tid] = h_in[b * 512 + (j - E_ - ENC_)];
    }
}

// ============ LSTM gates ============
__global__ void k_gates(const float* __restrict__ pz, const float* __restrict__ bl,
                        const float* __restrict__ c_in, const int* __restrict__ slen, int t,
                        float* __restrict__ c_out, float* __restrict__ h_out)
{
    int tid = blockIdx.x * 256 + threadIdx.x;   // 16384
    int b = tid >> 9, l = tid & 511;
    float zi = 0.f, zf = 0.f, zg = 0.f, zo = 0.f;
    for (int c = 0; c < ZCH; ++c) {
        const float* row = pz + (size_t)c * (B_ * ZN_) + b * ZN_;
        zi += row[l]; zf += row[512 + l]; zg += row[1024 + l]; zo += row[1536 + l];
    }
    zi += bl[l]; zf += bl[512 + l]; zg += bl[1024 + l]; zo += bl[1536 + l];
    float si = 1.f / (1.f + expf(-zi));
    float sf = 1.f / (1.f + expf(-zf));
    float so = 1.f / (1.f + expf(-zo));
    float g  = tanhf(zg);
    float cn = sf * c_in[tid] + si * g;
    float hn = so * tanhf(cn);
    float mf = (slen[b] > t) ? 1.f : 0.f;
    c_out[tid] = cn * mf;
    h_out[tid] = hn * mf;
}

// ============ pred combine ============
__global__ void k_pred(const float* __restrict__ pp, const float* __restrict__ bo,
                       const int* __restrict__ slen, int t, float* __restrict__ out)
{
    int tid = blockIdx.x * 256 + threadIdx.x;   // 320000
    if (tid >= B_ * V_) return;
    int b = tid / V_, v = tid - b * V_;
    float s = 0.f;
    for (int c = 0; c < 4; ++c) s += pp[(size_t)c * (B_ * V_) + tid];
    s += bo[v];
    float mf = (slen[b] > t) ? 1.f : 0.f;
    out[((size_t)b * STEPS + t) * V_ + v] = s * mf;
}

extern "C" void kernel_launch(void* const* d_in, const int* in_sizes, int n_in,
                              void* d_out, int out_size, void* d_ws, size_t ws_size,
                              hipStream_t stream)
{
    const float* enc  = (const float*)d_in[0];
    const int*   seqs = (const int*)  d_in[1];
    const float* emb  = (const float*)d_in[2];
    const float* Wea  = (const float*)d_in[3];
    const float* bea  = (const float*)d_in[4];
    const float* Wga  = (const float*)d_in[5];
    const float* bga  = (const float*)d_in[6];
    const float* Wfa  = (const float*)d_in[7];
    const float* bfa  = (const float*)d_in[8];
    const float* Wl   = (const float*)d_in[9];
    const float* Ul   = (const float*)d_in[10];
    const float* bl   = (const float*)d_in[11];
    const float* Wim  = (const float*)d_in[12];
    const float* bim  = (const float*)d_in[13];
    const float* Wic  = (const float*)d_in[14];
    const float* bic  = (const float*)d_in[15];
    const float* Wb   = (const float*)d_in[16];
    const float* bb   = (const float*)d_in[17];
    const float* Wo   = (const float*)d_in[18];
    const float* bo   = (const float*)d_in[19];

    float* out = (float*)d_out;
    float* ws  = (float*)d_ws;
    int* ord  = (int*)(ws + WS_ORD);
    int* slen = (int*)(ws + WS_SLEN);
    ushort_t* WeaT = (ushort_t*)(ws + WS_WEAT);
    ushort_t* a1b  = (ushort_t*)(ws + WS_A1B);
    ushort_t* WluB = (ushort_t*)(ws + WS_WLUB);
    ushort_t* WoB  = (ushort_t*)(ws + WS_WOB);
    ushort_t* WbB  = (ushort_t*)(ws + WS_WBB);
    ushort_t* WgaB = (ushort_t*)(ws + WS_WGAB);

    // ---- prologue ----
    k_order<<<1, 64, 0, stream>>>(seqs, ord, slen, out + OUT_ORDER);
    k_mean<<<256, 256, 0, stream>>>(enc, ord, ws + WS_MEAN);
    sg_partial<<<dim3(2, 16, 2), 256, 0, stream>>>(ws + WS_MEAN, Wim, ws + WS_PH, 2048, 512, 128, 0);
    sg_partial<<<dim3(2, 16, 2), 256, 0, stream>>>(ws + WS_MEAN, Wic, ws + WS_PH, 2048, 512, 128, 16);
    k_h0c0<<<128, 256, 0, stream>>>(ws + WS_PH, bim, bic, ws + WS_HBUF, ws + WS_CBUF);
    // weight casts (independent buffers; any order)
    k_cast<<<20480, 256, 0, stream>>>(Wl, WluB, 2560 * 2048);
    k_cast<<<4096, 256, 0, stream>>>(Ul, WluB + 2560 * 2048, 512 * 2048);
    k_cast<<<20000, 256, 0, stream>>>(Wo, WoB, 512 * 10000);
    k_cast<<<4096, 256, 0, stream>>>(Wb, WbB, 512 * 2048);
    k_cast<<<1024, 256, 0, stream>>>(Wga, WgaB, 512 * 512);
    k_castWT<<<4096, 256, 0, stream>>>(Wea, WeaT);
    k_a1_mfma<<<dim3(49, 4), 256, 0, stream>>>(enc, WeaT, bea, ord, a1b);

    // ---- decode steps ----
    for (int t = 0; t < STEPS; ++t) {
        float* h_in  = ws + WS_HBUF + (t & 1) * (B_ * L_);
        float* h_out = ws + WS_HBUF + ((t + 1) & 1) * (B_ * L_);
        float* c_in  = ws + WS_CBUF + (t & 1) * (B_ * L_);
        float* c_out = ws + WS_CBUF + ((t + 1) & 1) * (B_ * L_);

        k_attn<<<32, 256, 0, stream>>>(c_in, WgaB, bga, Wfa, bfa, a1b,
                                       ws + WS_ALPHA, out + OUT_ALPHA, slen, t);
        k_awe<<<256, 256, 0, stream>>>(ws + WS_ALPHA, enc, ord, ws + WS_AWE);
        sg_bf<<<dim3(8, 4, 2), 256, 0, stream>>>(c_in, WbB, ws + WS_PB, 512, 2048, 128, 0);
        k_buildx<<<384, 256, 0, stream>>>(ws + WS_PB, bb, ws + WS_AWE, emb, seqs, ord,
                                          h_in, t, ws + WS_X);
        sg_bf<<<dim3(8, ZCH, 2), 256, 0, stream>>>(ws + WS_X, WluB, ws + WS_PZ, 3072, 2048, 128, 0);
        k_gates<<<64, 256, 0, stream>>>(ws + WS_PZ, bl, c_in, slen, t, c_out, h_out);
        sg_bf<<<dim3(40, 4, 2), 256, 0, stream>>>(c_out, WoB, ws + WS_PP, 512, 10000, 128, 0);
        k_pred<<<1250, 256, 0, stream>>>(ws + WS_PP, bo, slen, t, out + OUT_PRED);
    }
}